// Round 1
// baseline (560.400 us; speedup 1.0000x reference)
//
#include <hip/hip_runtime.h>

#define NPTS 300000
#define LOG2T 19
#define TSIZE (1u<<LOG2T)

typedef float f32x4 __attribute__((ext_vector_type(4)));
typedef __bf16 bf16x8 __attribute__((ext_vector_type(8)));

__device__ __forceinline__ unsigned short f2bf(float f){
  unsigned u = __builtin_bit_cast(unsigned, f);
  u += 0x7fffu + ((u>>16)&1u);          // round-to-nearest-even
  return (unsigned short)(u>>16);
}

// swizzled byte offset within a 64x64 bf16 (8KB) per-wave buffer
__device__ __forceinline__ int swz(int row, int bytecol){
  return (row*128 + bytecol) ^ ((row & 7) << 4);
}

// ---------------- weight prep: f32 [K][N] -> bf16 B-fragments ----------------
struct WP { const float* p[17]; };

__device__ const int LK[17]  = {32,64, 64,64,64, 64,64,64, 64,64,64, 64,64,64, 64,64,64};
__device__ const int LN[17]  = {64,64, 64,64, 3, 64,64, 3, 64,64, 4, 64,64, 1, 64,64,48};
__device__ const int LNT[17] = { 4, 4,  4, 4, 1,  4, 4, 1,  4, 4, 1,  4, 4, 1,  4, 4, 3};
__device__ const int LOFF[17]= {0,4096, 12288,20480,28672, 30720,38912,47104,
                                49152,57344,65536, 67584,75776,83968, 86016,94208,102400};

__global__ void prep_weights(WP wp, unsigned short* dst){
  int gtid = blockIdx.x*blockDim.x + threadIdx.x;
  int gstr = blockDim.x*gridDim.x;
  for(int layer=0; layer<17; layer++){
    const float* W = wp.p[layer];
    int K = LK[layer], Nn = LN[layer], NT = LNT[layer];
    unsigned short* d = dst + LOFF[layer]/2;
    int nel = (K/32) * NT * 512;
    for(int i=gtid; i<nel; i += gstr){
      int j = i & 7, l = (i>>3)&63, fidx = i>>9;
      int kt = fidx / NT, nt = fidx - kt*NT;
      int k = kt*32 + ((l>>4)<<3) + j;
      int n = nt*16 + (l&15);
      unsigned short v = 0;
      if(n < Nn) v = f2bf(W[k*Nn + n]);
      d[i] = v;
    }
  }
}

// ---------------- MLP building blocks ----------------
template<int KT, int NT>
__device__ __forceinline__ void mlp_hidden(const char* bin, char* bout,
                                           const char* wbase, int lane){
  const int q = lane>>4, r = lane&15;
  bf16x8 a[4][KT];
  #pragma unroll
  for(int kt=0;kt<KT;kt++)
    #pragma unroll
    for(int mt=0;mt<4;mt++)
      a[mt][kt] = *(const bf16x8*)(bin + swz(r + 16*mt, kt*64 + q*16));
  const bf16x8* wf = (const bf16x8*)wbase;
  bf16x8 b[NT][KT];
  #pragma unroll
  for(int kt=0;kt<KT;kt++)
    #pragma unroll
    for(int nt=0;nt<NT;nt++)
      b[nt][kt] = wf[(kt*NT+nt)*64 + lane];
  f32x4 acc[4][NT];
  #pragma unroll
  for(int mt=0;mt<4;mt++)
    #pragma unroll
    for(int nt=0;nt<NT;nt++)
      acc[mt][nt] = f32x4{0.f,0.f,0.f,0.f};
  #pragma unroll
  for(int kt=0;kt<KT;kt++)
    #pragma unroll
    for(int mt=0;mt<4;mt++)
      #pragma unroll
      for(int nt=0;nt<NT;nt++)
        acc[mt][nt] = __builtin_amdgcn_mfma_f32_16x16x32_bf16(a[mt][kt], b[nt][kt], acc[mt][nt], 0,0,0);
  #pragma unroll
  for(int mt=0;mt<4;mt++)
    #pragma unroll
    for(int nt=0;nt<NT;nt++)
      #pragma unroll
      for(int rr=0;rr<4;rr++){
        float v = fmaxf(acc[mt][nt][rr], 0.f);
        *(unsigned short*)(bout + swz(16*mt + 4*q + rr, 2*(r + 16*nt))) = f2bf(v);
      }
}

template<int NT>
__device__ __forceinline__ void mlp_final(const char* bin, const char* wbase,
                                          int lane, f32x4 (&acc)[4][NT]){
  const int q = lane>>4, r = lane&15;
  bf16x8 a[4][2];
  #pragma unroll
  for(int kt=0;kt<2;kt++)
    #pragma unroll
    for(int mt=0;mt<4;mt++)
      a[mt][kt] = *(const bf16x8*)(bin + swz(r + 16*mt, kt*64 + q*16));
  const bf16x8* wf = (const bf16x8*)wbase;
  #pragma unroll
  for(int mt=0;mt<4;mt++)
    #pragma unroll
    for(int nt=0;nt<NT;nt++)
      acc[mt][nt] = f32x4{0.f,0.f,0.f,0.f};
  #pragma unroll
  for(int kt=0;kt<2;kt++)
    #pragma unroll
    for(int nt=0;nt<NT;nt++){
      bf16x8 b = wf[(kt*NT+nt)*64 + lane];
      #pragma unroll
      for(int mt=0;mt<4;mt++)
        acc[mt][nt] = __builtin_amdgcn_mfma_f32_16x16x32_bf16(a[mt][kt], b, acc[mt][nt], 0,0,0);
    }
}

template<int NT>
__device__ __forceinline__ void head_store(f32x4 (&acc)[4][NT], const float* resid,
    float* outp, int od, int pb, int lane, const unsigned char* mk){
  const int q = lane>>4, r = lane&15;
  #pragma unroll
  for(int mt=0;mt<4;mt++)
    #pragma unroll
    for(int rr=0;rr<4;rr++){
      int prow = 16*mt + 4*q + rr;
      int p = pb + prow;
      if(p >= NPTS) continue;
      float m = mk[prow] ? 1.f : 0.f;
      #pragma unroll
      for(int nt=0;nt<NT;nt++){
        int n = r + 16*nt;
        if(n < od){
          size_t idx = (size_t)p*od + n;
          outp[idx] = resid[idx] + m*acc[mt][nt][rr];
        }
      }
    }
}

// ---------------- fused kernel ----------------
__global__ __launch_bounds__(256,2) void fused(
    const float* __restrict__ xyz, const float* __restrict__ scales,
    const float* __restrict__ rots, const float* __restrict__ opac,
    const float* __restrict__ shs, const float* __restrict__ timep,
    const float* __restrict__ bmin, const float* __restrict__ bmax,
    const float* __restrict__ table, const unsigned short* __restrict__ wsw,
    float* __restrict__ out)
{
  __shared__ __align__(16) char lds[4][2][8192];
  __shared__ unsigned char mlds[4][64];
  const int w = threadIdx.x>>6, lane = threadIdx.x&63;
  const int pb = (blockIdx.x*4 + w)*64;
  char* b0 = &lds[w][0][0];
  char* b1 = &lds[w][1][0];

  // ---- encode phase: this thread owns point pb+lane ----
  {
    int p = pb + lane;
    bool valid = p < NPTS;
    float c0=0.f,c1=0.f,c2=0.f,c3=0.f;
    unsigned char mk = 0;
    if(valid){
      float x = xyz[3*p], y = xyz[3*p+1], z = xyz[3*p+2];
      float m0=bmin[0], m1=bmin[1], m2=bmin[2];
      float M0=bmax[0], M1=bmax[1], M2=bmax[2];
      c0 = (x-m0)/(M0-m0); c1 = (y-m1)/(M1-m1); c2 = (z-m2)/(M2-m2);
      mk = (c0>=0.f && c0<=1.f && c1>=0.f && c1<=1.f && c2>=0.f && c2<=1.f) ? 1 : 0;
      c3 = timep[p];
      c0 = fminf(fmaxf(c0,0.f),1.f);
      c1 = fminf(fmaxf(c1,0.f),1.f);
      c2 = fminf(fmaxf(c2,0.f),1.f);
      c3 = fminf(fmaxf(c3,0.f),1.f);
    }
    mlds[w][lane] = mk;
    if(valid){
      #pragma unroll 2
      for(int lv=0; lv<16; lv++){
        float sc = (float)(16<<lv) - 1.0f;
        float pos0 = c0*sc + 0.5f, pos1 = c1*sc + 0.5f;
        float pos2 = c2*sc + 0.5f, pos3 = c3*sc + 0.5f;
        float f0 = floorf(pos0), f1 = floorf(pos1), f2 = floorf(pos2), f3 = floorf(pos3);
        float w0 = pos0-f0, w1 = pos1-f1, w2 = pos2-f2, w3 = pos3-f3;
        unsigned i0 = (unsigned)f0, i1 = (unsigned)f1, i2 = (unsigned)f2, i3 = (unsigned)f3;
        unsigned hx0 = i0,                 hx1 = i0 + 1u;
        unsigned hy0 = i1*2654435761u,     hy1 = hy0 + 2654435761u;
        unsigned hz0 = i2*805459861u,      hz1 = hz0 + 805459861u;
        unsigned ht0 = i3*3674653429u,     ht1 = ht0 + 3674653429u;
        float u0=1.f-w0, u1=1.f-w1, u2=1.f-w2, u3=1.f-w3;
        float wxy[4] = {u0*u1, w0*u1, u0*w1, w0*w1};
        float wzt[4] = {u2*u3, w2*u3, u2*w3, w2*w3};
        const float* tb = table + ((size_t)lv<<20);
        float a0 = 0.f, a1 = 0.f;
        #pragma unroll
        for(int c=0;c<16;c++){
          unsigned h = ((c&1)?hx1:hx0) ^ ((c&2)?hy1:hy0) ^ ((c&4)?hz1:hz0) ^ ((c&8)?ht1:ht0);
          h &= (TSIZE-1u);
          float2 f = *(const float2*)(tb + ((size_t)h<<1));
          float wc = wxy[c&3]*wzt[c>>2];
          a0 = fmaf(f.x, wc, a0);
          a1 = fmaf(f.y, wc, a1);
        }
        unsigned pk = (unsigned)f2bf(a0) | ((unsigned)f2bf(a1)<<16);
        *(unsigned*)(b0 + swz(lane, 4*lv)) = pk;
      }
    } else {
      #pragma unroll
      for(int lv=0; lv<16; lv++) *(unsigned*)(b0 + swz(lane, 4*lv)) = 0u;
    }
  }

  // ---- MLP phase (per-wave private; no barriers needed) ----
  const char* wsb = (const char*)wsw;
  const unsigned char* mk = &mlds[w][0];

  mlp_hidden<1,4>(b0, b1, wsb+0,     lane);   // enc0: K=32
  mlp_hidden<2,4>(b1, b0, wsb+4096,  lane);   // enc1 -> shared hidden in b0

  f32x4 accs[4][1];
  f32x4 acc3[4][3];

  // xyz head
  mlp_hidden<2,4>(b0, b1, wsb+12288, lane);
  mlp_hidden<2,4>(b1, b1, wsb+20480, lane);
  mlp_final<1>(b1, wsb+28672, lane, accs);
  head_store<1>(accs, xyz, out, 3, pb, lane, mk);

  // scales head
  mlp_hidden<2,4>(b0, b1, wsb+30720, lane);
  mlp_hidden<2,4>(b1, b1, wsb+38912, lane);
  mlp_final<1>(b1, wsb+47104, lane, accs);
  head_store<1>(accs, scales, out + (size_t)3*NPTS, 3, pb, lane, mk);

  // rotations head
  mlp_hidden<2,4>(b0, b1, wsb+49152, lane);
  mlp_hidden<2,4>(b1, b1, wsb+57344, lane);
  mlp_final<1>(b1, wsb+65536, lane, accs);
  head_store<1>(accs, rots, out + (size_t)6*NPTS, 4, pb, lane, mk);

  // opacity head
  mlp_hidden<2,4>(b0, b1, wsb+67584, lane);
  mlp_hidden<2,4>(b1, b1, wsb+75776, lane);
  mlp_final<1>(b1, wsb+83968, lane, accs);
  head_store<1>(accs, opac, out + (size_t)10*NPTS, 1, pb, lane, mk);

  // shs head
  mlp_hidden<2,4>(b0, b1, wsb+86016, lane);
  mlp_hidden<2,4>(b1, b1, wsb+94208, lane);
  mlp_final<3>(b1, wsb+102400, lane, acc3);
  head_store<3>(acc3, shs, out + (size_t)11*NPTS, 48, pb, lane, mk);
}

extern "C" void kernel_launch(void* const* d_in, const int* in_sizes, int n_in,
                              void* d_out, int out_size, void* d_ws, size_t ws_size,
                              hipStream_t stream){
  (void)in_sizes; (void)n_in; (void)out_size; (void)ws_size;
  WP wp;
  for(int i=0;i<17;i++) wp.p[i] = (const float*)d_in[9+i];
  unsigned short* wsw = (unsigned short*)d_ws;
  prep_weights<<<64,256,0,stream>>>(wp, wsw);
  fused<<<1172,256,0,stream>>>(
      (const float*)d_in[0], (const float*)d_in[1], (const float*)d_in[2],
      (const float*)d_in[3], (const float*)d_in[4], (const float*)d_in[5],
      (const float*)d_in[6], (const float*)d_in[7], (const float*)d_in[8],
      wsw, (float*)d_out);
}